// Round 1
// baseline (236.195 us; speedup 1.0000x reference)
//
#include <hip/hip_runtime.h>
#include <math.h>

#define BB 64
#define TT 2048
#define DD 256
#define SS 16
#define CEPS 1e-8f

// ---------------- Kernel 1: per-segment means ----------------
// grid = BB*2*SS blocks, 256 threads. Threads: d4 = tid&63 (float4 over D),
// r = tid>>6 (4-way parallel over t). Coalesced 1KB per iteration.
__global__ void seg_mean_kernel(const float* __restrict__ feat,
                                const int* __restrict__ idx_pos,
                                const int* __restrict__ idx_neg,
                                float* __restrict__ means,   // [BB][2][SS][DD]
                                int* __restrict__ validf) {  // [BB][2][SS]
    int blk = blockIdx.x;
    int b   = blk >> 5;
    int ss  = blk & 31;
    int set = ss >> 4;
    int s   = ss & 15;
    const int* row = (set == 0 ? idx_pos : idx_neg) + b * 32;

    // valid = cumprod(starts >= 0) up to and including s
    int v = 1;
    for (int j = 0; j <= s; ++j) v &= (row[2 * j] >= 0) ? 1 : 0;

    int start = row[2 * s];
    int end   = row[2 * s + 1];
    int seg_len = end - start;
    if (seg_len < 1) seg_len = 1;
    int t0 = start < 0 ? 0 : start;
    int t1 = start + seg_len;
    if (t1 > TT) t1 = TT;

    int tid = threadIdx.x;
    int d4  = tid & 63;
    int r   = tid >> 6;

    float4 acc = make_float4(0.f, 0.f, 0.f, 0.f);
    if (v) {
        const float4* fp = (const float4*)(feat + (size_t)b * TT * DD);
        for (int t = t0 + r; t < t1; t += 4) {
            float4 x = fp[(size_t)t * 64 + d4];
            acc.x += x.x; acc.y += x.y; acc.z += x.z; acc.w += x.w;
        }
    }

    __shared__ float4 red[256];
    red[tid] = acc;
    __syncthreads();
    if (r == 0) {
        float4 a0 = red[d4];
        float4 a1 = red[d4 + 64];
        float4 a2 = red[d4 + 128];
        float4 a3 = red[d4 + 192];
        float inv = 1.0f / (float)seg_len;
        float4 m;
        m.x = (a0.x + a1.x + a2.x + a3.x) * inv;
        m.y = (a0.y + a1.y + a2.y + a3.y) * inv;
        m.z = (a0.z + a1.z + a2.z + a3.z) * inv;
        m.w = (a0.w + a1.w + a2.w + a3.w) * inv;
        float4* mp = (float4*)(means + (((size_t)b * 2 + set) * SS + s) * DD);
        mp[d4] = m;  // zeros when invalid (acc stayed 0)
    }
    if (tid == 0) validf[(b * 2 + set) * SS + s] = v;
}

// ---------------- block-wide pair reduction (256 threads = 4 waves) ----------
__device__ __forceinline__ float2 block_reduce2(float x, float y, float* sbuf) {
#pragma unroll
    for (int off = 32; off > 0; off >>= 1) {
        x += __shfl_down(x, off, 64);
        y += __shfl_down(y, off, 64);
    }
    int wave = threadIdx.x >> 6;
    int lane = threadIdx.x & 63;
    if (lane == 0) { sbuf[wave] = x; sbuf[4 + wave] = y; }
    __syncthreads();
    float rx = sbuf[0] + sbuf[1] + sbuf[2] + sbuf[3];
    float ry = sbuf[4] + sbuf[5] + sbuf[6] + sbuf[7];
    __syncthreads();   // protect sbuf for next call
    return make_float2(rx, ry);
}

// ---------------- Kernel 2: per-batch loss ----------------
// one block per batch, 256 threads (thread d owns dim d).
__global__ void loss_kernel(const float* __restrict__ means,
                            const int* __restrict__ validf,
                            float* __restrict__ loss_b) {
    __shared__ float sbuf[8];
    int b = blockIdx.x;
    int d = threadIdx.x;
    const float* pm = means + (size_t)b * 2 * SS * DD;
    const float* nm = pm + SS * DD;
    const int* pv = validf + b * 2 * SS;
    const int* nv = pv + SS;

    int pcnt = 0, ncnt = 0;
    for (int s = 0; s < SS; ++s) { pcnt += (pv[s] != 0); ncnt += (nv[s] != 0); }

    // center (invalid means are zero, matching reference sum over all s)
    float c = 0.f;
#pragma unroll
    for (int s = 0; s < SS; ++s) c += pm[s * DD + d];
    float pc = (float)pcnt;
    c /= pc;

    float2 rc = block_reduce2(c * c, 0.f, sbuf);
    float nc = fmaxf(sqrtf(rc.x), CEPS);

    float loss1 = 0.f;
    for (int s = 0; s < SS; ++s) {
        float a = pm[s * DD + d];
        float2 r2 = block_reduce2(a * c, a * a, sbuf);
        float na = fmaxf(sqrtf(r2.y), CEPS);
        float cosv = r2.x / (na * nc);
        if (pv[s]) loss1 += 1.0f - cosv;
    }
    float loss2 = 0.f;
    for (int s = 0; s < SS; ++s) {
        float a = nm[s * DD + d];
        float2 r2 = block_reduce2(a * c, a * a, sbuf);
        float na = fmaxf(sqrtf(r2.y), CEPS);
        float cosv = r2.x / (na * nc);
        if (nv[s]) loss2 += expf(cosv - 1.0f);
    }
    if (d == 0) loss_b[b] = loss1 / pc + loss2 / (float)ncnt;
}

// ---------------- Kernel 3: final mean over batches ----------------
__global__ void final_kernel(const float* __restrict__ loss_b,
                             float* __restrict__ out) {
    float x = loss_b[threadIdx.x];  // 64 threads == BB
#pragma unroll
    for (int off = 32; off > 0; off >>= 1) x += __shfl_down(x, off, 64);
    if (threadIdx.x == 0) out[0] = x / (float)BB;
}

extern "C" void kernel_launch(void* const* d_in, const int* in_sizes, int n_in,
                              void* d_out, int out_size, void* d_ws, size_t ws_size,
                              hipStream_t stream) {
    const float* feat = (const float*)d_in[0];
    const int* ipos   = (const int*)d_in[1];
    const int* ineg   = (const int*)d_in[2];
    float* out = (float*)d_out;

    char* ws = (char*)d_ws;
    size_t means_bytes = (size_t)BB * 2 * SS * DD * sizeof(float);   // 2 MiB
    size_t valid_bytes = (size_t)BB * 2 * SS * sizeof(int);          // 8 KiB
    float* means  = (float*)ws;
    int*   validf = (int*)(ws + means_bytes);
    float* loss_b = (float*)(ws + means_bytes + valid_bytes);

    seg_mean_kernel<<<BB * 2 * SS, 256, 0, stream>>>(feat, ipos, ineg, means, validf);
    loss_kernel<<<BB, 256, 0, stream>>>(means, validf, loss_b);
    final_kernel<<<1, 64, 0, stream>>>(loss_b, out);
}

// Round 2
// 202.885 us; speedup vs baseline: 1.1642x; 1.1642x over previous
//
#include <hip/hip_runtime.h>
#include <math.h>

#define BB 64
#define TT 2048
#define DD 256
#define SS 16
#define CEPS 1e-8f

// ---------------- Kernel 1: per-segment means ----------------
// grid = BB*2*SS = 2048 blocks, 256 threads. d4 = tid&63 (float4 over D=256),
// r = tid>>6 (4-way over t). Unroll x4 over t -> 4 independent loads in flight.
__global__ __launch_bounds__(256) void seg_mean_kernel(
        const float* __restrict__ feat,
        const int* __restrict__ idx_pos,
        const int* __restrict__ idx_neg,
        float* __restrict__ means,   // [BB][2][SS][DD]
        int* __restrict__ validf) {  // [BB][2][SS]
    int blk = blockIdx.x;
    int b   = blk >> 5;
    int ss  = blk & 31;
    int set = ss >> 4;
    int s   = ss & 15;
    const int* row = (set == 0 ? idx_pos : idx_neg) + b * 32;

    // valid = cumprod(starts >= 0) up to and including s
    int v = 1;
    for (int j = 0; j <= s; ++j) v &= (row[2 * j] >= 0) ? 1 : 0;

    int start = row[2 * s];
    int end   = row[2 * s + 1];
    int seg_len = end - start;
    if (seg_len < 1) seg_len = 1;
    int t0 = start < 0 ? 0 : start;
    int t1 = start + seg_len;
    if (t1 > TT) t1 = TT;

    int tid = threadIdx.x;
    int d4  = tid & 63;
    int r   = tid >> 6;

    float4 a0 = make_float4(0.f, 0.f, 0.f, 0.f);
    float4 a1 = a0, a2 = a0, a3 = a0;
    if (v) {
        const float4* fp = (const float4*)(feat + (size_t)b * TT * DD);
        int t = t0 + r;
        // rows for this thread: t, t+4, t+8, ... ; process 4 at a time
        for (; t + 12 < t1; t += 16) {
            float4 x0 = fp[(size_t)t * 64 + d4];
            float4 x1 = fp[(size_t)(t + 4) * 64 + d4];
            float4 x2 = fp[(size_t)(t + 8) * 64 + d4];
            float4 x3 = fp[(size_t)(t + 12) * 64 + d4];
            a0.x += x0.x; a0.y += x0.y; a0.z += x0.z; a0.w += x0.w;
            a1.x += x1.x; a1.y += x1.y; a1.z += x1.z; a1.w += x1.w;
            a2.x += x2.x; a2.y += x2.y; a2.z += x2.z; a2.w += x2.w;
            a3.x += x3.x; a3.y += x3.y; a3.z += x3.z; a3.w += x3.w;
        }
        for (; t < t1; t += 4) {
            float4 x = fp[(size_t)t * 64 + d4];
            a0.x += x.x; a0.y += x.y; a0.z += x.z; a0.w += x.w;
        }
    }
    float4 acc;
    acc.x = (a0.x + a1.x) + (a2.x + a3.x);
    acc.y = (a0.y + a1.y) + (a2.y + a3.y);
    acc.z = (a0.z + a1.z) + (a2.z + a3.z);
    acc.w = (a0.w + a1.w) + (a2.w + a3.w);

    __shared__ float4 red[256];
    red[tid] = acc;
    __syncthreads();
    if (r == 0) {
        float4 b0 = red[d4];
        float4 b1 = red[d4 + 64];
        float4 b2 = red[d4 + 128];
        float4 b3 = red[d4 + 192];
        float inv = 1.0f / (float)seg_len;
        float4 m;
        m.x = ((b0.x + b1.x) + (b2.x + b3.x)) * inv;
        m.y = ((b0.y + b1.y) + (b2.y + b3.y)) * inv;
        m.z = ((b0.z + b1.z) + (b2.z + b3.z)) * inv;
        m.w = ((b0.w + b1.w) + (b2.w + b3.w)) * inv;
        float4* mp = (float4*)(means + (((size_t)b * 2 + set) * SS + s) * DD);
        mp[d4] = m;  // zeros when invalid
    }
    if (tid == 0) validf[(b * 2 + set) * SS + s] = v;
}

// ---------------- Kernel 2: per-batch loss + final mean (fused) ----------------
// one block per batch, 256 threads. One barrier-based reduce (center norm),
// then 4 waves independently handle 8 segments each (shuffle-only reduces).
__global__ __launch_bounds__(256) void loss_kernel(
        const float* __restrict__ means,
        const int* __restrict__ validf,
        float* __restrict__ out) {
    __shared__ float cs[DD];
    __shared__ float wred[4];
    __shared__ float wl1[4], wl2[4];

    int b = blockIdx.x;
    int tid = threadIdx.x;
    int lane = tid & 63;
    int wave = tid >> 6;

    const float* pm = means + (size_t)b * 2 * SS * DD;
    const int* pv = validf + b * 2 * SS;  // 32 ints: pos[0..15], neg[16..31]

    int pcnt = 0, ncnt = 0;
#pragma unroll
    for (int s = 0; s < SS; ++s) { pcnt += (pv[s] != 0); ncnt += (pv[SS + s] != 0); }
    float pc = (float)pcnt;

    // center (thread tid owns dim tid); invalid means are zero, matching ref
    float c = 0.f;
#pragma unroll
    for (int s = 0; s < SS; ++s) c += pm[s * DD + tid];
    c /= pc;
    cs[tid] = c;

    float cc = c * c;
#pragma unroll
    for (int off = 32; off > 0; off >>= 1) cc += __shfl_down(cc, off, 64);
    if (lane == 0) wred[wave] = cc;
    __syncthreads();  // covers cs[] writes too
    float ncen = fmaxf(sqrtf((wred[0] + wred[1]) + (wred[2] + wred[3])), CEPS);

    float l1 = 0.f, l2 = 0.f;
    for (int g = wave; g < 2 * SS; g += 4) {
        const float* m = pm + g * DD;
        float dot = 0.f, nn = 0.f;
#pragma unroll
        for (int k = 0; k < 4; ++k) {
            int d = lane + 64 * k;
            float a = m[d];
            dot += a * cs[d];
            nn  += a * a;
        }
#pragma unroll
        for (int off = 32; off > 0; off >>= 1) {
            dot += __shfl_down(dot, off, 64);
            nn  += __shfl_down(nn, off, 64);
        }
        if (lane == 0) {
            float na = fmaxf(sqrtf(nn), CEPS);
            float cosv = dot / (na * ncen);
            if (g < SS) { if (pv[g]) l1 += 1.0f - cosv; }
            else        { if (pv[g]) l2 += expf(cosv - 1.0f); }
        }
    }
    if (lane == 0) { wl1[wave] = l1; wl2[wave] = l2; }
    __syncthreads();
    if (tid == 0) {
        float L1 = (wl1[0] + wl1[1]) + (wl1[2] + wl1[3]);
        float L2 = (wl2[0] + wl2[1]) + (wl2[2] + wl2[3]);
        float val = L1 / pc + L2 / (float)ncnt;
        atomicAdd(out, val * (1.0f / (float)BB));
    }
}

extern "C" void kernel_launch(void* const* d_in, const int* in_sizes, int n_in,
                              void* d_out, int out_size, void* d_ws, size_t ws_size,
                              hipStream_t stream) {
    const float* feat = (const float*)d_in[0];
    const int* ipos   = (const int*)d_in[1];
    const int* ineg   = (const int*)d_in[2];
    float* out = (float*)d_out;

    char* ws = (char*)d_ws;
    size_t means_bytes = (size_t)BB * 2 * SS * DD * sizeof(float);   // 2 MiB
    float* means  = (float*)ws;
    int*   validf = (int*)(ws + means_bytes);

    hipMemsetAsync(out, 0, sizeof(float), stream);  // capturable memset node
    seg_mean_kernel<<<BB * 2 * SS, 256, 0, stream>>>(feat, ipos, ineg, means, validf);
    loss_kernel<<<BB, 256, 0, stream>>>(means, validf, out);
}

// Round 3
// 198.699 us; speedup vs baseline: 1.1887x; 1.0211x over previous
//
#include <hip/hip_runtime.h>
#include <math.h>

#define BB 64
#define TT 2048
#define DD 256
#define SS 16
#define HH 4          // blocks per segment (load-balance split)
#define CEPS 1e-8f

// ---------------- Kernel 1: per-segment partial means ----------------
// grid = BB*2*SS*HH = 8192 blocks, 256 threads. Each block sums a contiguous
// quarter of its segment's rows, pre-scaled by 1/seg_len, into partials.
// d4 = tid&63 (float4 over D=256), r = tid>>6 (4-way over t), x4 t-unroll.
__global__ __launch_bounds__(256) void seg_mean_kernel(
        const float* __restrict__ feat,
        const int* __restrict__ idx_pos,
        const int* __restrict__ idx_neg,
        float* __restrict__ partials,  // [BB][2][SS][HH][DD]
        int* __restrict__ validf) {    // [BB][2][SS]
    int blk  = blockIdx.x;
    int b    = blk >> 7;
    int rest = blk & 127;
    int set  = rest >> 6;
    int s    = (rest >> 2) & 15;
    int h    = rest & 3;
    const int* row = (set == 0 ? idx_pos : idx_neg) + b * 32;

    // valid = cumprod(starts >= 0) up to and including s
    int v = 1;
    for (int j = 0; j <= s; ++j) v &= (row[2 * j] >= 0) ? 1 : 0;

    int start = row[2 * s];
    int end   = row[2 * s + 1];
    int seg_len = end - start;
    if (seg_len < 1) seg_len = 1;
    int t0 = start < 0 ? 0 : start;
    int t1 = start + seg_len;
    if (t1 > TT) t1 = TT;
    int len = t1 - t0;
    if (len < 0) len = 0;

    // this block's quarter of the row range
    int q0 = t0 + ((len * h) >> 2);
    int q1 = t0 + ((len * (h + 1)) >> 2);

    int tid = threadIdx.x;
    int d4  = tid & 63;
    int r   = tid >> 6;

    float4 a0 = make_float4(0.f, 0.f, 0.f, 0.f);
    float4 a1 = a0, a2 = a0, a3 = a0;
    if (v) {
        const float4* fp = (const float4*)(feat + (size_t)b * TT * DD);
        int t = q0 + r;
        for (; t + 12 < q1; t += 16) {
            float4 x0 = fp[(size_t)t * 64 + d4];
            float4 x1 = fp[(size_t)(t + 4) * 64 + d4];
            float4 x2 = fp[(size_t)(t + 8) * 64 + d4];
            float4 x3 = fp[(size_t)(t + 12) * 64 + d4];
            a0.x += x0.x; a0.y += x0.y; a0.z += x0.z; a0.w += x0.w;
            a1.x += x1.x; a1.y += x1.y; a1.z += x1.z; a1.w += x1.w;
            a2.x += x2.x; a2.y += x2.y; a2.z += x2.z; a2.w += x2.w;
            a3.x += x3.x; a3.y += x3.y; a3.z += x3.z; a3.w += x3.w;
        }
        for (; t < q1; t += 4) {
            float4 x = fp[(size_t)t * 64 + d4];
            a0.x += x.x; a0.y += x.y; a0.z += x.z; a0.w += x.w;
        }
    }
    float4 acc;
    acc.x = (a0.x + a1.x) + (a2.x + a3.x);
    acc.y = (a0.y + a1.y) + (a2.y + a3.y);
    acc.z = (a0.z + a1.z) + (a2.z + a3.z);
    acc.w = (a0.w + a1.w) + (a2.w + a3.w);

    __shared__ float4 red[256];
    red[tid] = acc;
    __syncthreads();
    if (r == 0) {
        float4 b0 = red[d4];
        float4 b1 = red[d4 + 64];
        float4 b2 = red[d4 + 128];
        float4 b3 = red[d4 + 192];
        float inv = 1.0f / (float)seg_len;
        float4 m;
        m.x = ((b0.x + b1.x) + (b2.x + b3.x)) * inv;
        m.y = ((b0.y + b1.y) + (b2.y + b3.y)) * inv;
        m.z = ((b0.z + b1.z) + (b2.z + b3.z)) * inv;
        m.w = ((b0.w + b1.w) + (b2.w + b3.w)) * inv;
        float4* mp = (float4*)(partials +
            ((((size_t)b * 2 + set) * SS + s) * HH + h) * DD);
        mp[d4] = m;  // zeros when invalid
    }
    if (tid == 0 && h == 0) validf[(b * 2 + set) * SS + s] = v;
}

// ---------------- Kernel 2: per-batch loss + final mean (fused) ----------------
// one block per batch, 256 threads. Thread d owns dim d. Segment mean =
// sum of its HH partials (already scaled by 1/len).
__global__ __launch_bounds__(256) void loss_kernel(
        const float* __restrict__ partials,  // [2*SS][HH][DD] per batch
        const int* __restrict__ validf,
        float* __restrict__ out) {
    __shared__ float cs[DD];
    __shared__ float wred[4];
    __shared__ float wl1[4], wl2[4];

    int b = blockIdx.x;
    int tid = threadIdx.x;
    int lane = tid & 63;
    int wave = tid >> 6;

    const float* pp = partials + (size_t)b * 2 * SS * HH * DD;
    const int* pv = validf + b * 2 * SS;  // 32 ints: pos[0..15], neg[16..31]

    int pcnt = 0, ncnt = 0;
#pragma unroll
    for (int s = 0; s < SS; ++s) { pcnt += (pv[s] != 0); ncnt += (pv[SS + s] != 0); }
    float pc = (float)pcnt;

    // center (thread tid owns dim tid); invalid means are zero, matching ref
    float c = 0.f;
#pragma unroll
    for (int s = 0; s < SS; ++s) {
        float m = 0.f;
#pragma unroll
        for (int h = 0; h < HH; ++h) m += pp[(s * HH + h) * DD + tid];
        c += m;
    }
    c /= pc;
    cs[tid] = c;

    float cc = c * c;
#pragma unroll
    for (int off = 32; off > 0; off >>= 1) cc += __shfl_down(cc, off, 64);
    if (lane == 0) wred[wave] = cc;
    __syncthreads();  // covers cs[] writes too
    float ncen = fmaxf(sqrtf((wred[0] + wred[1]) + (wred[2] + wred[3])), CEPS);

    float l1 = 0.f, l2 = 0.f;
    for (int g = wave; g < 2 * SS; g += 4) {
        const float* mg = pp + (size_t)g * HH * DD;
        float dot = 0.f, nn = 0.f;
#pragma unroll
        for (int k = 0; k < 4; ++k) {
            int d = lane + 64 * k;
            float a = ((mg[d] + mg[DD + d]) + (mg[2 * DD + d] + mg[3 * DD + d]));
            dot += a * cs[d];
            nn  += a * a;
        }
#pragma unroll
        for (int off = 32; off > 0; off >>= 1) {
            dot += __shfl_down(dot, off, 64);
            nn  += __shfl_down(nn, off, 64);
        }
        if (lane == 0) {
            float na = fmaxf(sqrtf(nn), CEPS);
            float cosv = dot / (na * ncen);
            if (g < SS) { if (pv[g]) l1 += 1.0f - cosv; }
            else        { if (pv[g]) l2 += expf(cosv - 1.0f); }
        }
    }
    if (lane == 0) { wl1[wave] = l1; wl2[wave] = l2; }
    __syncthreads();
    if (tid == 0) {
        float L1 = (wl1[0] + wl1[1]) + (wl1[2] + wl1[3]);
        float L2 = (wl2[0] + wl2[1]) + (wl2[2] + wl2[3]);
        float val = L1 / pc + L2 / (float)ncnt;
        atomicAdd(out, val * (1.0f / (float)BB));
    }
}

extern "C" void kernel_launch(void* const* d_in, const int* in_sizes, int n_in,
                              void* d_out, int out_size, void* d_ws, size_t ws_size,
                              hipStream_t stream) {
    const float* feat = (const float*)d_in[0];
    const int* ipos   = (const int*)d_in[1];
    const int* ineg   = (const int*)d_in[2];
    float* out = (float*)d_out;

    char* ws = (char*)d_ws;
    size_t part_bytes = (size_t)BB * 2 * SS * HH * DD * sizeof(float);  // 8 MiB
    float* partials = (float*)ws;
    int*   validf   = (int*)(ws + part_bytes);

    hipMemsetAsync(out, 0, sizeof(float), stream);  // capturable memset node
    seg_mean_kernel<<<BB * 2 * SS * HH, 256, 0, stream>>>(feat, ipos, ineg,
                                                          partials, validf);
    loss_kernel<<<BB, 256, 0, stream>>>(partials, validf, out);
}

// Round 4
// 197.476 us; speedup vs baseline: 1.1961x; 1.0062x over previous
//
#include <hip/hip_runtime.h>
#include <math.h>

#define BB 64
#define TT 2048
#define DD 256
#define SS 16
#define HH 4          // blocks per segment (load-balance split)
#define CEPS 1e-8f

// ---------------- Kernel 1: per-segment partial means ----------------
// grid = BB*2*SS*HH = 8192 blocks, 256 threads. Each block sums a contiguous
// quarter of its segment's rows, pre-scaled by 1/seg_len, into partials.
// XCD swizzle: low 3 bits of blockIdx = b%8, so all 128 blocks of one batch
// land on one XCD consecutively -> pos/neg overlapping rows hit that XCD's L2
// (2 batches resident at ~8 blocks/CU = 4MB feat = L2 size).
__global__ __launch_bounds__(256) void seg_mean_kernel(
        const float* __restrict__ feat,
        const int* __restrict__ idx_pos,
        const int* __restrict__ idx_neg,
        float* __restrict__ partials,  // [BB][2][SS][HH][DD]
        int* __restrict__ validf) {    // [BB][2][SS]
    int blk   = blockIdx.x;
    int xcd   = blk & 7;
    int inner = blk >> 3;          // 0..1023
    int work  = inner & 127;       // (set,s,h)
    int bg    = inner >> 7;        // 0..7
    int b     = bg * 8 + xcd;
    int set   = work >> 6;
    int s     = (work >> 2) & 15;
    int h     = work & 3;
    const int* row = (set == 0 ? idx_pos : idx_neg) + b * 32;

    // valid = cumprod(starts >= 0) up to and including s
    int v = 1;
    for (int j = 0; j <= s; ++j) v &= (row[2 * j] >= 0) ? 1 : 0;

    int start = row[2 * s];
    int end   = row[2 * s + 1];
    int seg_len = end - start;
    if (seg_len < 1) seg_len = 1;
    int t0 = start < 0 ? 0 : start;
    int t1 = start + seg_len;
    if (t1 > TT) t1 = TT;
    int len = t1 - t0;
    if (len < 0) len = 0;

    // this block's quarter of the row range
    int q0 = t0 + ((len * h) >> 2);
    int q1 = t0 + ((len * (h + 1)) >> 2);

    int tid = threadIdx.x;
    int d4  = tid & 63;
    int r   = tid >> 6;

    float4 a0 = make_float4(0.f, 0.f, 0.f, 0.f);
    float4 a1 = a0, a2 = a0, a3 = a0;
    if (v) {
        const float4* fp = (const float4*)(feat + (size_t)b * TT * DD);
        int t = q0 + r;
        for (; t + 12 < q1; t += 16) {
            float4 x0 = fp[(size_t)t * 64 + d4];
            float4 x1 = fp[(size_t)(t + 4) * 64 + d4];
            float4 x2 = fp[(size_t)(t + 8) * 64 + d4];
            float4 x3 = fp[(size_t)(t + 12) * 64 + d4];
            a0.x += x0.x; a0.y += x0.y; a0.z += x0.z; a0.w += x0.w;
            a1.x += x1.x; a1.y += x1.y; a1.z += x1.z; a1.w += x1.w;
            a2.x += x2.x; a2.y += x2.y; a2.z += x2.z; a2.w += x2.w;
            a3.x += x3.x; a3.y += x3.y; a3.z += x3.z; a3.w += x3.w;
        }
        for (; t < q1; t += 4) {
            float4 x = fp[(size_t)t * 64 + d4];
            a0.x += x.x; a0.y += x.y; a0.z += x.z; a0.w += x.w;
        }
    }
    float4 acc;
    acc.x = (a0.x + a1.x) + (a2.x + a3.x);
    acc.y = (a0.y + a1.y) + (a2.y + a3.y);
    acc.z = (a0.z + a1.z) + (a2.z + a3.z);
    acc.w = (a0.w + a1.w) + (a2.w + a3.w);

    __shared__ float4 red[256];
    red[tid] = acc;
    __syncthreads();
    if (r == 0) {
        float4 b0 = red[d4];
        float4 b1 = red[d4 + 64];
        float4 b2 = red[d4 + 128];
        float4 b3 = red[d4 + 192];
        float inv = 1.0f / (float)seg_len;
        float4 m;
        m.x = ((b0.x + b1.x) + (b2.x + b3.x)) * inv;
        m.y = ((b0.y + b1.y) + (b2.y + b3.y)) * inv;
        m.z = ((b0.z + b1.z) + (b2.z + b3.z)) * inv;
        m.w = ((b0.w + b1.w) + (b2.w + b3.w)) * inv;
        float4* mp = (float4*)(partials +
            ((((size_t)b * 2 + set) * SS + s) * HH + h) * DD);
        mp[d4] = m;  // zeros when invalid
    }
    if (tid == 0 && h == 0) validf[(b * 2 + set) * SS + s] = v;
}

// ---------------- Kernel 2: per-batch loss + final mean (fused) ----------------
// one block per batch, 256 threads. Thread d owns dim d. Segment mean =
// sum of its HH partials (already scaled by 1/len).
__global__ __launch_bounds__(256) void loss_kernel(
        const float* __restrict__ partials,  // [2*SS][HH][DD] per batch
        const int* __restrict__ validf,
        float* __restrict__ out) {
    __shared__ float cs[DD];
    __shared__ float wred[4];
    __shared__ float wl1[4], wl2[4];

    int b = blockIdx.x;   // b%8 == blockIdx%8 -> same XCD that wrote partials
    int tid = threadIdx.x;
    int lane = tid & 63;
    int wave = tid >> 6;

    const float* pp = partials + (size_t)b * 2 * SS * HH * DD;
    const int* pv = validf + b * 2 * SS;  // 32 ints: pos[0..15], neg[16..31]

    int pcnt = 0, ncnt = 0;
#pragma unroll
    for (int s = 0; s < SS; ++s) { pcnt += (pv[s] != 0); ncnt += (pv[SS + s] != 0); }
    float pc = (float)pcnt;

    // center (thread tid owns dim tid); invalid means are zero, matching ref
    float c = 0.f;
#pragma unroll
    for (int s = 0; s < SS; ++s) {
        float m = 0.f;
#pragma unroll
        for (int h = 0; h < HH; ++h) m += pp[(s * HH + h) * DD + tid];
        c += m;
    }
    c /= pc;
    cs[tid] = c;

    float cc = c * c;
#pragma unroll
    for (int off = 32; off > 0; off >>= 1) cc += __shfl_down(cc, off, 64);
    if (lane == 0) wred[wave] = cc;
    __syncthreads();  // covers cs[] writes too
    float ncen = fmaxf(sqrtf((wred[0] + wred[1]) + (wred[2] + wred[3])), CEPS);

    float l1 = 0.f, l2 = 0.f;
    for (int g = wave; g < 2 * SS; g += 4) {
        const float* mg = pp + (size_t)g * HH * DD;
        float dot = 0.f, nn = 0.f;
#pragma unroll
        for (int k = 0; k < 4; ++k) {
            int d = lane + 64 * k;
            float a = ((mg[d] + mg[DD + d]) + (mg[2 * DD + d] + mg[3 * DD + d]));
            dot += a * cs[d];
            nn  += a * a;
        }
#pragma unroll
        for (int off = 32; off > 0; off >>= 1) {
            dot += __shfl_down(dot, off, 64);
            nn  += __shfl_down(nn, off, 64);
        }
        if (lane == 0) {
            float na = fmaxf(sqrtf(nn), CEPS);
            float cosv = dot / (na * ncen);
            if (g < SS) { if (pv[g]) l1 += 1.0f - cosv; }
            else        { if (pv[g]) l2 += expf(cosv - 1.0f); }
        }
    }
    if (lane == 0) { wl1[wave] = l1; wl2[wave] = l2; }
    __syncthreads();
    if (tid == 0) {
        float L1 = (wl1[0] + wl1[1]) + (wl1[2] + wl1[3]);
        float L2 = (wl2[0] + wl2[1]) + (wl2[2] + wl2[3]);
        float val = L1 / pc + L2 / (float)ncnt;
        atomicAdd(out, val * (1.0f / (float)BB));
    }
}

extern "C" void kernel_launch(void* const* d_in, const int* in_sizes, int n_in,
                              void* d_out, int out_size, void* d_ws, size_t ws_size,
                              hipStream_t stream) {
    const float* feat = (const float*)d_in[0];
    const int* ipos   = (const int*)d_in[1];
    const int* ineg   = (const int*)d_in[2];
    float* out = (float*)d_out;

    char* ws = (char*)d_ws;
    size_t part_bytes = (size_t)BB * 2 * SS * HH * DD * sizeof(float);  // 8 MiB
    float* partials = (float*)ws;
    int*   validf   = (int*)(ws + part_bytes);

    hipMemsetAsync(out, 0, sizeof(float), stream);  // capturable memset node
    seg_mean_kernel<<<BB * 2 * SS * HH, 256, 0, stream>>>(feat, ipos, ineg,
                                                          partials, validf);
    loss_kernel<<<BB, 256, 0, stream>>>(partials, validf, out);
}